// Round 7
// baseline (433.203 us; speedup 1.0000x reference)
//
#include <hip/hip_runtime.h>
#include <math.h>

// Problem: B=4, S=8192, H=2048, K=4, fp32. Causal depthwise conv + SiLU.
// R7: single-variable change vs R1/R6 — FULL-ROW blocks. Each block's 256
// threads cover all 512 float4 groups of a row (2 columns per thread, 4KB
// apart), so the block's memory footprint is a CONTIGUOUS 256KB span
// (TT=32 rows x 8KB), instead of 4KB chunks strided by 8KB. Targets DRAM
// page/row-buffer efficiency (the suspected 0.6x throughput limiter).
// NT loads + NT stores + natural compiler schedule kept identical to R1.
#define CB 4
#define CS 8192
#define CH 2048
#define CH4 (CH / 4)      // 512 float4 groups per row
#define TT 32             // timesteps per block (halo 3/32 = 9.4%)
#define TSTRIPS (CS / TT) // 256

typedef float f4 __attribute__((ext_vector_type(4)));

__device__ __forceinline__ f4 silu4(f4 v) {
    f4 r;
    r.x = v.x * __builtin_amdgcn_rcpf(1.0f + __expf(-v.x));
    r.y = v.y * __builtin_amdgcn_rcpf(1.0f + __expf(-v.y));
    r.z = v.z * __builtin_amdgcn_rcpf(1.0f + __expf(-v.z));
    r.w = v.w * __builtin_amdgcn_rcpf(1.0f + __expf(-v.w));
    return r;
}

__device__ __forceinline__ f4 conv4(f4 w0, f4 w1, f4 w2, f4 w3,
                                    f4 m3, f4 m2, f4 m1, f4 c) {
    f4 o;
    o.x = w0.x * m3.x + w0.y * m2.x + w0.z * m1.x + w0.w * c.x;
    o.y = w1.x * m3.y + w1.y * m2.y + w1.z * m1.y + w1.w * c.y;
    o.z = w2.x * m3.z + w2.y * m2.z + w2.z * m1.z + w2.w * c.z;
    o.w = w3.x * m3.w + w3.y * m2.w + w3.z * m1.w + w3.w * c.w;
    return o;
}

__global__ __launch_bounds__(256) void dwconv_silu_kernel(
        const float* __restrict__ x,
        const float* __restrict__ w,
        float* __restrict__ y) {
    const int thr = threadIdx.x;
    const int blk = blockIdx.x;
    const int b   = blk >> 8;                    // / TSTRIPS
    const int t0  = (blk & (TSTRIPS - 1)) * TT;

    const size_t base = (size_t)b * CS * CH4 + (size_t)t0 * CH4;
    // Column A: groups 0..255, column B: groups 256..511 of each row.
    const f4* __restrict__ xA = (const f4*)x + base + thr;
    const f4* __restrict__ xB = xA + 256;
    f4* __restrict__ yA = (f4*)y + base + thr;
    f4* __restrict__ yB = yA + 256;

    // Weight taps: channel group h4 uses wv[h4*4 + 0..3].
    const f4* __restrict__ wv = (const f4*)w;
    const f4 wA0 = wv[(size_t)thr * 4 + 0], wA1 = wv[(size_t)thr * 4 + 1];
    const f4 wA2 = wv[(size_t)thr * 4 + 2], wA3 = wv[(size_t)thr * 4 + 3];
    const f4 wB0 = wv[(size_t)(thr + 256) * 4 + 0], wB1 = wv[(size_t)(thr + 256) * 4 + 1];
    const f4 wB2 = wv[(size_t)(thr + 256) * 4 + 2], wB3 = wv[(size_t)(thr + 256) * 4 + 3];

    // Sliding windows (rows t0-3..t0-1), zero at sequence start (t0 uniform
    // per block -> wave-uniform branch).
    f4 a3 = 0.f, a2 = 0.f, a1 = 0.f;
    f4 b3 = 0.f, b2 = 0.f, b1 = 0.f;
    if (t0 != 0) {
        a3 = __builtin_nontemporal_load(xA - 3 * CH4);
        a2 = __builtin_nontemporal_load(xA - 2 * CH4);
        a1 = __builtin_nontemporal_load(xA - 1 * CH4);
        b3 = __builtin_nontemporal_load(xB - 3 * CH4);
        b2 = __builtin_nontemporal_load(xB - 2 * CH4);
        b1 = __builtin_nontemporal_load(xB - 1 * CH4);
    }

    const f4* __restrict__ xa = xA;
    const f4* __restrict__ xb = xB;
    f4* __restrict__ ya = yA;
    f4* __restrict__ yb = yB;

    #pragma unroll 4
    for (int i = 0; i < TT; ++i) {
        const f4 curA = __builtin_nontemporal_load(xa);
        const f4 curB = __builtin_nontemporal_load(xb);

        f4 oA = conv4(wA0, wA1, wA2, wA3, a3, a2, a1, curA);
        f4 oB = conv4(wB0, wB1, wB2, wB3, b3, b2, b1, curB);

        __builtin_nontemporal_store(silu4(oA), ya);
        __builtin_nontemporal_store(silu4(oB), yb);

        a3 = a2; a2 = a1; a1 = curA;
        b3 = b2; b2 = b1; b1 = curB;
        xa += CH4; xb += CH4;
        ya += CH4; yb += CH4;
    }
}

extern "C" void kernel_launch(void* const* d_in, const int* in_sizes, int n_in,
                              void* d_out, int out_size, void* d_ws, size_t ws_size,
                              hipStream_t stream) {
    const float* x = (const float*)d_in[0];   // (B, S, H) fp32
    const float* w = (const float*)d_in[1];   // (H, K) fp32
    float* y = (float*)d_out;                 // (B, S, H) fp32

    const int blocks = CB * TSTRIPS;          // 4 * 256 = 1024
    dwconv_silu_kernel<<<blocks, 256, 0, stream>>>(x, w, y);
}